// Round 1
// baseline (415.630 us; speedup 1.0000x reference)
//
#include <hip/hip_runtime.h>

#define NTOK 1024
#define KSEL 256

// Workspace layout (floats):
//   P     [B][2][33][NTOK]  : per c-half projections.
//     part0 (xt channels): j0 = gx_w.xt (score_x), j1..8 = px_w@xt (a_x),
//                          j9..16 = pm_w@xt (b_m), j17..24 = prx_w@xt, j25..32 = prm_w@xt
//     part1 (mt channels): j0 = gm_w.mt (score_m), j1..8 = px_w@mt (a_m),
//                          j9..16 = pm_w@mt (b_x), j17..24 = prx_w@mt, j25..32 = prm_w@mt
//   masks [B][4][NTOK]      : tm_x, rm_x, tm_m, rm_m  (binary 0/1 floats)
//   G     [B][NTOK][8]      : fuse_x + fuse_m per token
#define P_OFF    0
#define P_SIZE   (32ull * 2 * 33 * NTOK)
#define MASK_OFF P_SIZE
#define MASK_SIZE (32ull * 4 * NTOK)
#define G_OFF    (P_SIZE + MASK_SIZE)

// ---------------- K1: skinny projection, reads all of x once ----------------
// grid = 32 b * 8 ntiles * 2 parts = 512 blocks, block = 128
__global__ __launch_bounds__(128) void k1_proj(
    const float* __restrict__ x,
    const float* __restrict__ gx_w, const float* __restrict__ gm_w,
    const float* __restrict__ px_w, const float* __restrict__ pm_w,
    const float* __restrict__ prx_w, const float* __restrict__ prm_w,
    float* __restrict__ P)
{
  int blk = blockIdx.x;
  int part = blk & 1;          // 0 = xt half, 1 = mt half
  int ntile = (blk >> 1) & 7;  // 8 tiles of 128 tokens
  int b = blk >> 4;
  int n = ntile * 128 + threadIdx.x;
  const float* gw = part ? gm_w : gx_w;
  int c0 = part * 384;

  float acc[33];
  #pragma unroll
  for (int j = 0; j < 33; ++j) acc[j] = 0.f;

  const float* xp = x + ((size_t)b * 768 + c0) * NTOK + n;
  #pragma unroll 8
  for (int c = 0; c < 384; ++c) {
    float v = xp[(size_t)c * NTOK];
    acc[0] = fmaf(gw[c], v, acc[0]);
    #pragma unroll
    for (int r = 0; r < 8; ++r) {
      acc[1 + r]  = fmaf(px_w[r * 384 + c],  v, acc[1 + r]);
      acc[9 + r]  = fmaf(pm_w[r * 384 + c],  v, acc[9 + r]);
      acc[17 + r] = fmaf(prx_w[r * 384 + c], v, acc[17 + r]);
      acc[25 + r] = fmaf(prm_w[r * 384 + c], v, acc[25 + r]);
    }
  }
  float* Pp = P + (((size_t)b * 2 + part) * 33) * NTOK + n;
  #pragma unroll
  for (int j = 0; j < 33; ++j) Pp[(size_t)j * NTOK] = acc[j];
}

// ---------------- K2: exact stable top-k / bottom-k masks ----------------
// grid = 32 b * 4 slots = 128 blocks, block = 1024 (one thread per token)
// slot: 0=tm_x, 1=rm_x, 2=tm_m, 3=rm_m
__global__ __launch_bounds__(1024) void k2_masks(
    const float* __restrict__ P, float* __restrict__ masks)
{
  __shared__ int wcnt[16];
  __shared__ int wpre[16];
  __shared__ int tot;
  int b = blockIdx.x >> 2;
  int slot = blockIdx.x & 3;
  int branch = slot >> 1;   // 0 = x, 1 = m
  int which = slot & 1;     // 0 = top-k, 1 = bottom-k
  int tid = threadIdx.x;
  int wid = tid >> 6;
  int lane = tid & 63;

  float s = P[(((size_t)b * 2 + branch) * 33) * NTOK + tid];
  s += 0.0f;  // canonicalize -0.0 -> +0.0
  unsigned bits = __float_as_uint(s);
  unsigned key = (bits & 0x80000000u) ? ~bits : (bits | 0x80000000u);
  if (which) key = ~key;  // bottom-k == top-k in reversed order
  unsigned long long lmask = (1ull << lane) - 1ull;

  // radix-select the 256th-largest key
  unsigned prefix = 0u;
  for (int bit = 31; bit >= 0; --bit) {
    unsigned cand = prefix | (1u << bit);
    unsigned long long bal = __ballot(key >= cand);
    if (lane == 0) wcnt[wid] = __popcll(bal);
    __syncthreads();
    if (tid == 0) {
      int t = 0;
      #pragma unroll
      for (int i = 0; i < 16; ++i) t += wcnt[i];
      tot = t;
    }
    __syncthreads();
    if (tot >= KSEL) prefix = cand;
    __syncthreads();
  }
  // prefix == T, the k-th largest key
  unsigned long long bal_gt = __ballot(key > prefix);
  if (lane == 0) wcnt[wid] = __popcll(bal_gt);
  __syncthreads();
  if (tid == 0) {
    int t = 0;
    #pragma unroll
    for (int i = 0; i < 16; ++i) t += wcnt[i];
    tot = t;
  }
  __syncthreads();
  int cnt_gt = tot;
  __syncthreads();
  // stable tie-break by index among key == T (matches jax.lax.top_k)
  unsigned long long bal_eq = __ballot(key == prefix);
  if (lane == 0) wcnt[wid] = __popcll(bal_eq);
  __syncthreads();
  if (tid == 0) {
    int run = 0;
    #pragma unroll
    for (int i = 0; i < 16; ++i) { wpre[i] = run; run += wcnt[i]; }
  }
  __syncthreads();
  int eqrank = wpre[wid] + __popcll(bal_eq & lmask);
  bool sel = (key > prefix) || ((key == prefix) && (eqrank < (KSEL - cnt_gt)));
  masks[((size_t)b * 4 + slot) * NTOK + tid] = sel ? 1.0f : 0.0f;
}

// ---------------- K3: per-token rank-8 fuse math ----------------
// grid = 64 blocks, block = 512 (one thread per (b,n))
__global__ __launch_bounds__(512) void k3_g(
    const float* __restrict__ P, const float* __restrict__ masks,
    const float* __restrict__ px_b, const float* __restrict__ pm_b,
    const float* __restrict__ prx_b, const float* __restrict__ prm_b,
    const float* __restrict__ pfx_w, const float* __restrict__ pfx_b,
    const float* __restrict__ pfm_w, const float* __restrict__ pfm_b,
    float* __restrict__ G)
{
  int idx = blockIdx.x * 512 + threadIdx.x;
  int b = idx >> 10;
  int n = idx & 1023;
  const float* P0 = P + ((size_t)b * 2 + 0) * 33 * NTOK + n;
  const float* P1 = P + ((size_t)b * 2 + 1) * 33 * NTOK + n;

  float ax[8], am[8], bxv[8], bmv[8], cx[8], cm[8];
  #pragma unroll
  for (int r = 0; r < 8; ++r) {
    ax[r]  = P0[(size_t)(1 + r) * NTOK];
    am[r]  = P1[(size_t)(1 + r) * NTOK];
    bmv[r] = P0[(size_t)(9 + r) * NTOK];
    bxv[r] = P1[(size_t)(9 + r) * NTOK];
    cx[r]  = P0[(size_t)(17 + r) * NTOK] + P1[(size_t)(17 + r) * NTOK];
    cm[r]  = P0[(size_t)(25 + r) * NTOK] + P1[(size_t)(25 + r) * NTOK];
  }
  const float* mk = masks + (size_t)b * 4 * NTOK + n;
  float tmx = mk[0 * NTOK], rmx = mk[1 * NTOK];
  float tmm = mk[2 * NTOK], rmm = mk[3 * NTOK];
  float wx = 1.0f - tmx - rmx;
  float wm = 1.0f - tmm - rmm;

  float lowx[8], lrx[8], lowm[8], lrm[8];
  #pragma unroll
  for (int r = 0; r < 8; ++r) {
    lowx[r] = fmaf(tmx, ax[r], fmaf(rmx, am[r], px_b[r]));
    lrx[r]  = fmaf(wx, cx[r], prx_b[r]);
    lowm[r] = fmaf(tmm, bxv[r], fmaf(rmm, bmv[r], pm_b[r]));
    lrm[r]  = fmaf(wm, cm[r], prm_b[r]);
  }
  float g[8];
  #pragma unroll
  for (int r = 0; r < 8; ++r) {
    float acc = pfx_b[r] + pfm_b[r];
    #pragma unroll
    for (int s = 0; s < 8; ++s) {
      acc = fmaf(pfx_w[r * 16 + s],     lowx[s], acc);
      acc = fmaf(pfx_w[r * 16 + 8 + s], lrx[s],  acc);
      acc = fmaf(pfm_w[r * 16 + s],     lowm[s], acc);
      acc = fmaf(pfm_w[r * 16 + 8 + s], lrm[s],  acc);
    }
    g[r] = acc;
  }
  float4* Gp = reinterpret_cast<float4*>(G + ((size_t)b * NTOK + n) * 8);
  Gp[0] = make_float4(g[0], g[1], g[2], g[3]);
  Gp[1] = make_float4(g[4], g[5], g[6], g[7]);
}

// ---------------- K4: rank-8 -> 384 expansion, writes output ----------------
// grid = 32 b * 8 ntiles * 4 cparts = 1024 blocks, block = 128
__global__ __launch_bounds__(128) void k4_out(
    const float* __restrict__ G, const float* __restrict__ pb_w,
    const float* __restrict__ pb_b, float* __restrict__ out)
{
  int blk = blockIdx.x;
  int cpart = blk & 3;          // 4 chunks of 96 output channels
  int ntile = (blk >> 2) & 7;   // 8 tiles of 128 tokens
  int b = blk >> 5;
  int n = ntile * 128 + threadIdx.x;

  const float4* Gp = reinterpret_cast<const float4*>(G + ((size_t)b * NTOK + n) * 8);
  float4 g0 = Gp[0], g1 = Gp[1];

  float* op = out + ((size_t)b * 384 + (size_t)cpart * 96) * NTOK + n;
  const float* wp = pb_w + (size_t)cpart * 96 * 8;
  const float* bp = pb_b + (size_t)cpart * 96;
  #pragma unroll 4
  for (int c = 0; c < 96; ++c) {
    const float* w = wp + c * 8;
    float acc = bp[c];
    acc = fmaf(w[0], g0.x, acc);
    acc = fmaf(w[1], g0.y, acc);
    acc = fmaf(w[2], g0.z, acc);
    acc = fmaf(w[3], g0.w, acc);
    acc = fmaf(w[4], g1.x, acc);
    acc = fmaf(w[5], g1.y, acc);
    acc = fmaf(w[6], g1.z, acc);
    acc = fmaf(w[7], g1.w, acc);
    op[(size_t)c * NTOK] = acc;
  }
}

extern "C" void kernel_launch(void* const* d_in, const int* in_sizes, int n_in,
                              void* d_out, int out_size, void* d_ws, size_t ws_size,
                              hipStream_t stream) {
  const float* x     = (const float*)d_in[0];
  const float* gx_w  = (const float*)d_in[1];
  const float* gm_w  = (const float*)d_in[3];
  const float* px_w  = (const float*)d_in[5];
  const float* px_b  = (const float*)d_in[6];
  const float* pm_w  = (const float*)d_in[7];
  const float* pm_b  = (const float*)d_in[8];
  const float* prx_w = (const float*)d_in[9];
  const float* prx_b = (const float*)d_in[10];
  const float* prm_w = (const float*)d_in[11];
  const float* prm_b = (const float*)d_in[12];
  const float* pfx_w = (const float*)d_in[13];
  const float* pfx_b = (const float*)d_in[14];
  const float* pfm_w = (const float*)d_in[15];
  const float* pfm_b = (const float*)d_in[16];
  const float* pb_w  = (const float*)d_in[17];
  const float* pb_b  = (const float*)d_in[18];
  float* out = (float*)d_out;

  float* ws = (float*)d_ws;
  float* P     = ws + P_OFF;
  float* masks = ws + MASK_OFF;
  float* G     = ws + G_OFF;

  k1_proj<<<512, 128, 0, stream>>>(x, gx_w, gm_w, px_w, pm_w, prx_w, prm_w, P);
  k2_masks<<<128, 1024, 0, stream>>>(P, masks);
  k3_g<<<64, 512, 0, stream>>>(P, masks, px_b, pm_b, prx_b, prm_b,
                               pfx_w, pfx_b, pfm_w, pfm_b, G);
  k4_out<<<1024, 128, 0, stream>>>(G, pb_w, pb_b, out);
}

// Round 4
// 306.705 us; speedup vs baseline: 1.3551x; 1.3551x over previous
//
#include <hip/hip_runtime.h>

#define NTOK 1024
#define KSEL 256

// Workspace layout (floats):
//   Ppart [NS][B][2][33][NTOK] : per-channel-split partial projections.
//     part0 (xt channels): j0 = gx_w.xt (score_x), j1..8 = px_w@xt,
//                          j9..16 = pm_w@xt, j17..24 = prx_w@xt, j25..32 = prm_w@xt
//     part1 (mt channels): j0 = gm_w.mt (score_m), j1..8 = px_w@mt,
//                          j9..16 = pm_w@mt, j17..24 = prx_w@mt, j25..32 = prm_w@mt
//   masks [B][4][NTOK]         : tm_x, rm_x, tm_m, rm_m (binary 0/1 floats)
//   G     [B][NTOK][8]         : fuse_x + fuse_m per token

// ---------------- K1: skinny projection, channel-split for occupancy ----------------
// CS = channels per split. grid = 32b * NS * 8 ntiles * 2 parts, block = 128.
template <int CS>
__global__ __launch_bounds__(128) void k1_proj(
    const float* __restrict__ x,
    const float* __restrict__ gx_w, const float* __restrict__ gm_w,
    const float* __restrict__ px_w, const float* __restrict__ pm_w,
    const float* __restrict__ prx_w, const float* __restrict__ prm_w,
    float* __restrict__ Pp)
{
  constexpr int NS = 384 / CS;
  constexpr int SB = (NS == 1) ? 0 : 2;  // NS is 1 or 4
  int blk = blockIdx.x;
  int part = blk & 1;              // 0 = xt half, 1 = mt half
  int ntile = (blk >> 1) & 7;      // 8 tiles of 128 tokens
  int s = (blk >> 4) & (NS - 1);   // channel split
  int b = blk >> (4 + SB);
  int n = ntile * 128 + threadIdx.x;
  const float* gw = part ? gm_w : gx_w;
  int cw0 = s * CS;                 // weight channel base

  float acc[33];
  #pragma unroll
  for (int j = 0; j < 33; ++j) acc[j] = 0.f;

  const float* xp = x + ((size_t)b * 768 + part * 384 + cw0) * NTOK + n;
  #pragma unroll 8
  for (int c = 0; c < CS; ++c) {
    float v = xp[(size_t)c * NTOK];
    int cw = cw0 + c;
    acc[0] = fmaf(gw[cw], v, acc[0]);
    #pragma unroll
    for (int r = 0; r < 8; ++r) {
      acc[1 + r]  = fmaf(px_w[r * 384 + cw],  v, acc[1 + r]);
      acc[9 + r]  = fmaf(pm_w[r * 384 + cw],  v, acc[9 + r]);
      acc[17 + r] = fmaf(prx_w[r * 384 + cw], v, acc[17 + r]);
      acc[25 + r] = fmaf(prm_w[r * 384 + cw], v, acc[25 + r]);
    }
  }
  float* op = Pp + ((((size_t)s * 32 + b) * 2 + part) * 33) * NTOK + n;
  #pragma unroll
  for (int j = 0; j < 33; ++j) op[(size_t)j * NTOK] = acc[j];
}

// ---------------- K2: exact stable top-k & bottom-k, one wave per row ----------------
// grid = 32 b * 2 branches = 64 blocks, block = 64 (1 wave). Scores in registers.
__global__ __launch_bounds__(64) void k2_masks(
    const float* __restrict__ Ppart, float* __restrict__ masks, int nsplit)
{
  int b = blockIdx.x >> 1;
  int branch = blockIdx.x & 1;
  int lane = threadIdx.x;
  unsigned long long lmask = (1ull << lane) - 1ull;

  // gather + reduce score partials: token = i*64 + lane
  float v[16];
  #pragma unroll
  for (int i = 0; i < 16; ++i) v[i] = 0.f;
  for (int s = 0; s < nsplit; ++s) {
    const float* sp = Ppart + (((size_t)s * 32 + b) * 2 + branch) * 33 * NTOK;
    #pragma unroll
    for (int i = 0; i < 16; ++i) v[i] += sp[i * 64 + lane];
  }
  unsigned key[16];
  #pragma unroll
  for (int i = 0; i < 16; ++i) {
    float f = v[i] + 0.0f;  // canonicalize -0.0
    unsigned bits = __float_as_uint(f);
    key[i] = (bits & 0x80000000u) ? ~bits : (bits | 0x80000000u);
  }

  for (int which = 0; which < 2; ++which) {  // 0 = top-k, 1 = bottom-k
    // radix-select the KSEL-th largest key
    unsigned prefix = 0u;
    for (int bit = 31; bit >= 0; --bit) {
      unsigned cand = prefix | (1u << bit);
      int cnt = 0;
      #pragma unroll
      for (int i = 0; i < 16; ++i) {
        unsigned kk = which ? ~key[i] : key[i];
        cnt += __popcll(__ballot(kk >= cand));
      }
      if (cnt >= KSEL) prefix = cand;
    }
    int cgt = 0;
    #pragma unroll
    for (int i = 0; i < 16; ++i) {
      unsigned kk = which ? ~key[i] : key[i];
      cgt += __popcll(__ballot(kk > prefix));
    }
    int quota = KSEL - cgt;
    // stable (lowest token index first) tie-break among key == T
    float* mp = masks + ((size_t)b * 4 + branch * 2 + which) * NTOK;
    int run = 0;
    #pragma unroll
    for (int i = 0; i < 16; ++i) {
      unsigned kk = which ? ~key[i] : key[i];
      bool eq = (kk == prefix);
      unsigned long long bal = __ballot(eq);
      int rank = run + __popcll(bal & lmask);
      bool sel = (kk > prefix) || (eq && rank < quota);
      mp[i * 64 + lane] = sel ? 1.0f : 0.0f;
      run += __popcll(bal);
    }
  }
}

// ---------------- K3: sum partials + per-token rank-8 fuse math ----------------
// grid = 128 blocks, block = 256 (one thread per (b,n))
template <int NS>
__global__ __launch_bounds__(256) void k3_g(
    const float* __restrict__ Ppart, const float* __restrict__ masks,
    const float* __restrict__ px_b, const float* __restrict__ pm_b,
    const float* __restrict__ prx_b, const float* __restrict__ prm_b,
    const float* __restrict__ pfx_w, const float* __restrict__ pfx_b,
    const float* __restrict__ pfm_w, const float* __restrict__ pfm_b,
    float* __restrict__ G)
{
  int idx = blockIdx.x * 256 + threadIdx.x;
  int b = idx >> 10;
  int n = idx & 1023;

  float ax[8], am[8], bxv[8], bmv[8], cx[8], cm[8];
  #pragma unroll
  for (int r = 0; r < 8; ++r) {
    ax[r] = am[r] = bxv[r] = bmv[r] = cx[r] = cm[r] = 0.f;
  }
  #pragma unroll
  for (int s = 0; s < NS; ++s) {
    const float* P0 = Ppart + (((size_t)s * 32 + b) * 2 + 0) * 33 * NTOK + n;
    const float* P1 = Ppart + (((size_t)s * 32 + b) * 2 + 1) * 33 * NTOK + n;
    #pragma unroll
    for (int r = 0; r < 8; ++r) {
      ax[r]  += P0[(size_t)(1 + r) * NTOK];
      am[r]  += P1[(size_t)(1 + r) * NTOK];
      bmv[r] += P0[(size_t)(9 + r) * NTOK];
      bxv[r] += P1[(size_t)(9 + r) * NTOK];
      cx[r]  += P0[(size_t)(17 + r) * NTOK] + P1[(size_t)(17 + r) * NTOK];
      cm[r]  += P0[(size_t)(25 + r) * NTOK] + P1[(size_t)(25 + r) * NTOK];
    }
  }
  const float* mk = masks + (size_t)b * 4 * NTOK + n;
  float tmx = mk[0 * NTOK], rmx = mk[1 * NTOK];
  float tmm = mk[2 * NTOK], rmm = mk[3 * NTOK];
  float wx = 1.0f - tmx - rmx;
  float wm = 1.0f - tmm - rmm;

  float lowx[8], lrx[8], lowm[8], lrm[8];
  #pragma unroll
  for (int r = 0; r < 8; ++r) {
    lowx[r] = fmaf(tmx, ax[r], fmaf(rmx, am[r], px_b[r]));
    lrx[r]  = fmaf(wx, cx[r], prx_b[r]);
    lowm[r] = fmaf(tmm, bxv[r], fmaf(rmm, bmv[r], pm_b[r]));
    lrm[r]  = fmaf(wm, cm[r], prm_b[r]);
  }
  float g[8];
  #pragma unroll
  for (int r = 0; r < 8; ++r) {
    float acc = pfx_b[r] + pfm_b[r];
    #pragma unroll
    for (int s2 = 0; s2 < 8; ++s2) {
      acc = fmaf(pfx_w[r * 16 + s2],     lowx[s2], acc);
      acc = fmaf(pfx_w[r * 16 + 8 + s2], lrx[s2],  acc);
      acc = fmaf(pfm_w[r * 16 + s2],     lowm[s2], acc);
      acc = fmaf(pfm_w[r * 16 + 8 + s2], lrm[s2],  acc);
    }
    g[r] = acc;
  }
  float4* Gp = reinterpret_cast<float4*>(G + ((size_t)b * NTOK + n) * 8);
  Gp[0] = make_float4(g[0], g[1], g[2], g[3]);
  Gp[1] = make_float4(g[4], g[5], g[6], g[7]);
}

// ---------------- K4: rank-8 -> 384 expansion, writes output ----------------
// grid = 32 b * 8 ntiles * 4 cparts = 1024 blocks, block = 128
__global__ __launch_bounds__(128) void k4_out(
    const float* __restrict__ G, const float* __restrict__ pb_w,
    const float* __restrict__ pb_b, float* __restrict__ out)
{
  int blk = blockIdx.x;
  int cpart = blk & 3;
  int ntile = (blk >> 2) & 7;
  int b = blk >> 5;
  int n = ntile * 128 + threadIdx.x;

  const float4* Gp = reinterpret_cast<const float4*>(G + ((size_t)b * NTOK + n) * 8);
  float4 g0 = Gp[0], g1 = Gp[1];

  float* op = out + ((size_t)b * 384 + (size_t)cpart * 96) * NTOK + n;
  const float* wp = pb_w + (size_t)cpart * 96 * 8;
  const float* bp = pb_b + (size_t)cpart * 96;
  #pragma unroll 4
  for (int c = 0; c < 96; ++c) {
    const float* w = wp + c * 8;
    float acc = bp[c];
    acc = fmaf(w[0], g0.x, acc);
    acc = fmaf(w[1], g0.y, acc);
    acc = fmaf(w[2], g0.z, acc);
    acc = fmaf(w[3], g0.w, acc);
    acc = fmaf(w[4], g1.x, acc);
    acc = fmaf(w[5], g1.y, acc);
    acc = fmaf(w[6], g1.z, acc);
    acc = fmaf(w[7], g1.w, acc);
    op[(size_t)c * NTOK] = acc;
  }
}

extern "C" void kernel_launch(void* const* d_in, const int* in_sizes, int n_in,
                              void* d_out, int out_size, void* d_ws, size_t ws_size,
                              hipStream_t stream) {
  const float* x     = (const float*)d_in[0];
  const float* gx_w  = (const float*)d_in[1];
  const float* gm_w  = (const float*)d_in[3];
  const float* px_w  = (const float*)d_in[5];
  const float* px_b  = (const float*)d_in[6];
  const float* pm_w  = (const float*)d_in[7];
  const float* pm_b  = (const float*)d_in[8];
  const float* prx_w = (const float*)d_in[9];
  const float* prx_b = (const float*)d_in[10];
  const float* prm_w = (const float*)d_in[11];
  const float* prm_b = (const float*)d_in[12];
  const float* pfx_w = (const float*)d_in[13];
  const float* pfx_b = (const float*)d_in[14];
  const float* pfm_w = (const float*)d_in[15];
  const float* pfm_b = (const float*)d_in[16];
  const float* pb_w  = (const float*)d_in[17];
  const float* pb_b  = (const float*)d_in[18];
  float* out = (float*)d_out;

  const size_t P1_F   = 32ull * 2 * 33 * NTOK;  // one split's P slab (floats)
  const size_t MASK_F = 32ull * 4 * NTOK;
  const size_t G_F    = 32ull * NTOK * 8;
  const size_t need4  = (4 * P1_F + MASK_F + G_F) * 4;  // bytes for nsplit=4

  float* ws = (float*)d_ws;
  if (ws_size >= need4) {
    float* Ppart = ws;
    float* masks = ws + 4 * P1_F;
    float* G     = masks + MASK_F;
    k1_proj<96><<<2048, 128, 0, stream>>>(x, gx_w, gm_w, px_w, pm_w, prx_w, prm_w, Ppart);
    k2_masks<<<64, 64, 0, stream>>>(Ppart, masks, 4);
    k3_g<4><<<128, 256, 0, stream>>>(Ppart, masks, px_b, pm_b, prx_b, prm_b,
                                     pfx_w, pfx_b, pfm_w, pfm_b, G);
    k4_out<<<1024, 128, 0, stream>>>(G, pb_w, pb_b, out);
  } else {
    float* Ppart = ws;
    float* masks = ws + P1_F;
    float* G     = masks + MASK_F;
    k1_proj<384><<<512, 128, 0, stream>>>(x, gx_w, gm_w, px_w, pm_w, prx_w, prm_w, Ppart);
    k2_masks<<<64, 64, 0, stream>>>(Ppart, masks, 1);
    k3_g<1><<<128, 256, 0, stream>>>(Ppart, masks, px_b, pm_b, prx_b, prm_b,
                                     pfx_w, pfx_b, pfm_w, pfm_b, G);
    k4_out<<<1024, 128, 0, stream>>>(G, pb_w, pb_b, out);
  }
}

// Round 5
// 300.226 us; speedup vs baseline: 1.3844x; 1.0216x over previous
//
#include <hip/hip_runtime.h>

#define NTOK 1024
#define KSEL 256

// Workspace layout (floats):
//   Ppart [NS][B][2][33][NTOK] : per-channel-split partial projections.
//     part0 (xt): j0 = gx_w.xt (score_x), j1..8 = px_w@xt, j9..16 = pm_w@xt,
//                 j17..24 = prx_w@xt, j25..32 = prm_w@xt
//     part1 (mt): j0 = gm_w.mt (score_m), j1..8 = px_w@mt, j9..16 = pm_w@mt,
//                 j17..24 = prx_w@mt, j25..32 = prm_w@mt
//   masks [B][4][NTOK]         : tm_x, rm_x, tm_m, rm_m (binary 0/1)
//   G     [B][NTOK][8]         : fuse_x + fuse_m per token
//   LOWS  [B][4][8][NTOK]      : kind 0=lowx 1=lrx 2=lowm 3=lrm

// ---------------- K1: skinny projection, 16-deep register prefetch ----------------
// grid = 32b * NS * 8 ntiles * 2 parts, block = 128 (2 waves).
template <int CS>
__global__ __launch_bounds__(128) void k1_proj(
    const float* __restrict__ x,
    const float* __restrict__ gx_w, const float* __restrict__ gm_w,
    const float* __restrict__ px_w, const float* __restrict__ pm_w,
    const float* __restrict__ prx_w, const float* __restrict__ prm_w,
    float* __restrict__ Pp)
{
  constexpr int NS = 384 / CS;
  constexpr int SB = (NS == 1) ? 0 : 2;  // NS is 1 or 4
  constexpr int NCB = CS / 16;           // 16-channel chunks
  int blk = blockIdx.x;
  int part = blk & 1;
  int ntile = (blk >> 1) & 7;
  int s = (blk >> 4) & (NS - 1);
  int b = blk >> (4 + SB);
  int n = ntile * 128 + threadIdx.x;
  const float* gw = part ? gm_w : gx_w;
  int cw0 = s * CS;

  float acc[33];
  #pragma unroll
  for (int j = 0; j < 33; ++j) acc[j] = 0.f;

  const float* xp = x + ((size_t)b * 768 + part * 384 + cw0) * NTOK + n;

  float cur[16], nxt[16];
  #pragma unroll
  for (int i = 0; i < 16; ++i) cur[i] = xp[(size_t)i * NTOK];

  #pragma unroll
  for (int cb = 0; cb < NCB; ++cb) {
    // prefetch next 16 channels (static guard under full unroll)
    #pragma unroll
    for (int i = 0; i < 16; ++i)
      nxt[i] = (cb + 1 < NCB) ? xp[(size_t)((cb + 1) * 16 + i) * NTOK] : 0.f;
    // consume current 16 channels
    #pragma unroll
    for (int i = 0; i < 16; ++i) {
      int cw = cw0 + cb * 16 + i;
      float v = cur[i];
      acc[0] = fmaf(gw[cw], v, acc[0]);
      #pragma unroll
      for (int r = 0; r < 8; ++r) {
        acc[1 + r]  = fmaf(px_w[r * 384 + cw],  v, acc[1 + r]);
        acc[9 + r]  = fmaf(pm_w[r * 384 + cw],  v, acc[9 + r]);
        acc[17 + r] = fmaf(prx_w[r * 384 + cw], v, acc[17 + r]);
        acc[25 + r] = fmaf(prm_w[r * 384 + cw], v, acc[25 + r]);
      }
    }
    #pragma unroll
    for (int i = 0; i < 16; ++i) cur[i] = nxt[i];
  }
  float* op = Pp + ((((size_t)s * 32 + b) * 2 + part) * 33) * NTOK + n;
  #pragma unroll
  for (int j = 0; j < 33; ++j) op[(size_t)j * NTOK] = acc[j];
}

// ---------------- K2: exact stable top-k & bottom-k, one wave per row ----------------
__global__ __launch_bounds__(64) void k2_masks(
    const float* __restrict__ Ppart, float* __restrict__ masks, int nsplit)
{
  int b = blockIdx.x >> 1;
  int branch = blockIdx.x & 1;
  int lane = threadIdx.x;
  unsigned long long lmask = (1ull << lane) - 1ull;

  float v[16];
  #pragma unroll
  for (int i = 0; i < 16; ++i) v[i] = 0.f;
  for (int s = 0; s < nsplit; ++s) {
    const float* sp = Ppart + (((size_t)s * 32 + b) * 2 + branch) * 33 * NTOK;
    #pragma unroll
    for (int i = 0; i < 16; ++i) v[i] += sp[i * 64 + lane];
  }
  unsigned key[16];
  #pragma unroll
  for (int i = 0; i < 16; ++i) {
    float f = v[i] + 0.0f;  // canonicalize -0.0
    unsigned bits = __float_as_uint(f);
    key[i] = (bits & 0x80000000u) ? ~bits : (bits | 0x80000000u);
  }

  for (int which = 0; which < 2; ++which) {
    unsigned prefix = 0u;
    for (int bit = 31; bit >= 0; --bit) {
      unsigned cand = prefix | (1u << bit);
      int cnt = 0;
      #pragma unroll
      for (int i = 0; i < 16; ++i) {
        unsigned kk = which ? ~key[i] : key[i];
        cnt += __popcll(__ballot(kk >= cand));
      }
      if (cnt >= KSEL) prefix = cand;
    }
    int cgt = 0;
    #pragma unroll
    for (int i = 0; i < 16; ++i) {
      unsigned kk = which ? ~key[i] : key[i];
      cgt += __popcll(__ballot(kk > prefix));
    }
    int quota = KSEL - cgt;
    float* mp = masks + ((size_t)b * 4 + branch * 2 + which) * NTOK;
    int run = 0;
    #pragma unroll
    for (int i = 0; i < 16; ++i) {
      unsigned kk = which ? ~key[i] : key[i];
      bool eq = (kk == prefix);
      unsigned long long bal = __ballot(eq);
      int rank = run + __popcll(bal & lmask);
      bool sel = (kk > prefix) || (eq && rank < quota);
      mp[i * 64 + lane] = sel ? 1.0f : 0.0f;
      run += __popcll(bal);
    }
  }
}

// ---------------- K3a: split-sum + mask apply, one thread per (token, r) ----------------
// grid = 32 b * 8 r = 256 blocks, block = 1024 (16 waves) -> 4096 waves.
template <int NS>
__global__ __launch_bounds__(1024) void k3a(
    const float* __restrict__ Ppart, const float* __restrict__ masks,
    const float* __restrict__ px_b, const float* __restrict__ pm_b,
    const float* __restrict__ prx_b, const float* __restrict__ prm_b,
    float* __restrict__ LOWS)
{
  int r = blockIdx.x & 7;
  int b = blockIdx.x >> 3;
  int n = threadIdx.x;

  float ax = 0.f, am = 0.f, bmv = 0.f, bxv = 0.f, cx = 0.f, cm = 0.f;
  #pragma unroll
  for (int s = 0; s < NS; ++s) {
    const float* P0 = Ppart + (((size_t)s * 32 + b) * 2 + 0) * 33 * NTOK + n;
    const float* P1 = Ppart + (((size_t)s * 32 + b) * 2 + 1) * 33 * NTOK + n;
    ax  += P0[(size_t)(1 + r) * NTOK];
    am  += P1[(size_t)(1 + r) * NTOK];
    bmv += P0[(size_t)(9 + r) * NTOK];
    bxv += P1[(size_t)(9 + r) * NTOK];
    cx  += P0[(size_t)(17 + r) * NTOK] + P1[(size_t)(17 + r) * NTOK];
    cm  += P0[(size_t)(25 + r) * NTOK] + P1[(size_t)(25 + r) * NTOK];
  }
  const float* mk = masks + (size_t)b * 4 * NTOK + n;
  float tmx = mk[0 * NTOK], rmx = mk[1 * NTOK];
  float tmm = mk[2 * NTOK], rmm = mk[3 * NTOK];
  float wx = 1.0f - tmx - rmx;
  float wm = 1.0f - tmm - rmm;

  float lowx = fmaf(tmx, ax, fmaf(rmx, am, px_b[r]));
  float lrx  = fmaf(wx, cx, prx_b[r]);
  float lowm = fmaf(tmm, bxv, fmaf(rmm, bmv, pm_b[r]));
  float lrm  = fmaf(wm, cm, prm_b[r]);

  float* L = LOWS + ((size_t)b * 32 + r) * NTOK + n;  // [b][kind][r][tok]
  L[0 * 8 * NTOK] = lowx;
  L[1 * 8 * NTOK] = lrx;
  L[2 * 8 * NTOK] = lowm;
  L[3 * 8 * NTOK] = lrm;
}

// ---------------- K3b: 8x32 fuse matmul per token ----------------
// grid = 32 blocks (one per b), block = 1024.
__global__ __launch_bounds__(1024) void k3b(
    const float* __restrict__ LOWS,
    const float* __restrict__ pfx_w, const float* __restrict__ pfx_b,
    const float* __restrict__ pfm_w, const float* __restrict__ pfm_b,
    float* __restrict__ G)
{
  int b = blockIdx.x;
  int n = threadIdx.x;
  const float* L = LOWS + (size_t)b * 32 * NTOK + n;
  float lowx[8], lrx[8], lowm[8], lrm[8];
  #pragma unroll
  for (int r = 0; r < 8; ++r) {
    lowx[r] = L[(size_t)(0 * 8 + r) * NTOK];
    lrx[r]  = L[(size_t)(1 * 8 + r) * NTOK];
    lowm[r] = L[(size_t)(2 * 8 + r) * NTOK];
    lrm[r]  = L[(size_t)(3 * 8 + r) * NTOK];
  }
  float g[8];
  #pragma unroll
  for (int r = 0; r < 8; ++r) {
    float acc = pfx_b[r] + pfm_b[r];
    #pragma unroll
    for (int s2 = 0; s2 < 8; ++s2) {
      acc = fmaf(pfx_w[r * 16 + s2],     lowx[s2], acc);
      acc = fmaf(pfx_w[r * 16 + 8 + s2], lrx[s2],  acc);
      acc = fmaf(pfm_w[r * 16 + s2],     lowm[s2], acc);
      acc = fmaf(pfm_w[r * 16 + 8 + s2], lrm[s2],  acc);
    }
    g[r] = acc;
  }
  float4* Gp = reinterpret_cast<float4*>(G + ((size_t)b * NTOK + n) * 8);
  Gp[0] = make_float4(g[0], g[1], g[2], g[3]);
  Gp[1] = make_float4(g[4], g[5], g[6], g[7]);
}

// ---------------- K4: rank-8 -> 384 expansion, dwordx4 stores ----------------
// grid = 32 b * 4 cparts * 4 ttiles = 512 blocks, block = 64 (1 wave), 4 tokens/thread.
__global__ __launch_bounds__(64) void k4_out(
    const float* __restrict__ G, const float* __restrict__ pb_w,
    const float* __restrict__ pb_b, float* __restrict__ out)
{
  int blk = blockIdx.x;
  int ttile = blk & 3;          // 4 tiles of 256 tokens
  int cpart = (blk >> 2) & 3;   // 4 chunks of 96 channels
  int b = blk >> 4;
  int n0 = ttile * 256 + threadIdx.x * 4;  // 4 consecutive tokens

  const float4* Gp = reinterpret_cast<const float4*>(G + ((size_t)b * NTOK + n0) * 8);
  float4 ga0 = Gp[0], ga1 = Gp[1];  // token n0
  float4 gb0 = Gp[2], gb1 = Gp[3];  // token n0+1
  float4 gc0 = Gp[4], gc1 = Gp[5];  // token n0+2
  float4 gd0 = Gp[6], gd1 = Gp[7];  // token n0+3

  float* op = out + ((size_t)b * 384 + (size_t)cpart * 96) * NTOK + n0;
  const float* wp = pb_w + (size_t)cpart * 96 * 8;
  const float* bp = pb_b + (size_t)cpart * 96;
  #pragma unroll 4
  for (int c = 0; c < 96; ++c) {
    const float* w = wp + c * 8;
    float w0 = w[0], w1 = w[1], w2 = w[2], w3 = w[3];
    float w4 = w[4], w5 = w[5], w6 = w[6], w7 = w[7];
    float bb = bp[c];
    float4 o;
    o.x = bb; o.y = bb; o.z = bb; o.w = bb;
    o.x = fmaf(w0, ga0.x, o.x); o.x = fmaf(w1, ga0.y, o.x);
    o.x = fmaf(w2, ga0.z, o.x); o.x = fmaf(w3, ga0.w, o.x);
    o.x = fmaf(w4, ga1.x, o.x); o.x = fmaf(w5, ga1.y, o.x);
    o.x = fmaf(w6, ga1.z, o.x); o.x = fmaf(w7, ga1.w, o.x);
    o.y = fmaf(w0, gb0.x, o.y); o.y = fmaf(w1, gb0.y, o.y);
    o.y = fmaf(w2, gb0.z, o.y); o.y = fmaf(w3, gb0.w, o.y);
    o.y = fmaf(w4, gb1.x, o.y); o.y = fmaf(w5, gb1.y, o.y);
    o.y = fmaf(w6, gb1.z, o.y); o.y = fmaf(w7, gb1.w, o.y);
    o.z = fmaf(w0, gc0.x, o.z); o.z = fmaf(w1, gc0.y, o.z);
    o.z = fmaf(w2, gc0.z, o.z); o.z = fmaf(w3, gc0.w, o.z);
    o.z = fmaf(w4, gc1.x, o.z); o.z = fmaf(w5, gc1.y, o.z);
    o.z = fmaf(w6, gc1.z, o.z); o.z = fmaf(w7, gc1.w, o.z);
    o.w = fmaf(w0, gd0.x, o.w); o.w = fmaf(w1, gd0.y, o.w);
    o.w = fmaf(w2, gd0.z, o.w); o.w = fmaf(w3, gd0.w, o.w);
    o.w = fmaf(w4, gd1.x, o.w); o.w = fmaf(w5, gd1.y, o.w);
    o.w = fmaf(w6, gd1.z, o.w); o.w = fmaf(w7, gd1.w, o.w);
    *reinterpret_cast<float4*>(op + (size_t)c * NTOK) = o;
  }
}

extern "C" void kernel_launch(void* const* d_in, const int* in_sizes, int n_in,
                              void* d_out, int out_size, void* d_ws, size_t ws_size,
                              hipStream_t stream) {
  const float* x     = (const float*)d_in[0];
  const float* gx_w  = (const float*)d_in[1];
  const float* gm_w  = (const float*)d_in[3];
  const float* px_w  = (const float*)d_in[5];
  const float* px_b  = (const float*)d_in[6];
  const float* pm_w  = (const float*)d_in[7];
  const float* pm_b  = (const float*)d_in[8];
  const float* prx_w = (const float*)d_in[9];
  const float* prx_b = (const float*)d_in[10];
  const float* prm_w = (const float*)d_in[11];
  const float* prm_b = (const float*)d_in[12];
  const float* pfx_w = (const float*)d_in[13];
  const float* pfx_b = (const float*)d_in[14];
  const float* pfm_w = (const float*)d_in[15];
  const float* pfm_b = (const float*)d_in[16];
  const float* pb_w  = (const float*)d_in[17];
  const float* pb_b  = (const float*)d_in[18];
  float* out = (float*)d_out;

  const size_t P1_F   = 32ull * 2 * 33 * NTOK;  // one split slab (floats)
  const size_t MASK_F = 32ull * 4 * NTOK;
  const size_t G_F    = 32ull * NTOK * 8;
  const size_t LOWS_F = 32ull * 32 * NTOK;
  const size_t need4  = (4 * P1_F + MASK_F + G_F + LOWS_F) * 4;

  float* ws = (float*)d_ws;
  if (ws_size >= need4) {
    float* Ppart = ws;
    float* masks = ws + 4 * P1_F;
    float* G     = masks + MASK_F;
    float* LOWS  = G + G_F;
    k1_proj<96><<<2048, 128, 0, stream>>>(x, gx_w, gm_w, px_w, pm_w, prx_w, prm_w, Ppart);
    k2_masks<<<64, 64, 0, stream>>>(Ppart, masks, 4);
    k3a<4><<<256, 1024, 0, stream>>>(Ppart, masks, px_b, pm_b, prx_b, prm_b, LOWS);
    k3b<<<32, 1024, 0, stream>>>(LOWS, pfx_w, pfx_b, pfm_w, pfm_b, G);
    k4_out<<<512, 64, 0, stream>>>(G, pb_w, pb_b, out);
  } else {
    float* Ppart = ws;
    float* masks = ws + P1_F;
    float* G     = masks + MASK_F;
    float* LOWS  = G + G_F;
    k1_proj<384><<<512, 128, 0, stream>>>(x, gx_w, gm_w, px_w, pm_w, prx_w, prm_w, Ppart);
    k2_masks<<<64, 64, 0, stream>>>(Ppart, masks, 1);
    k3a<1><<<256, 1024, 0, stream>>>(Ppart, masks, px_b, pm_b, prx_b, prm_b, LOWS);
    k3b<<<32, 1024, 0, stream>>>(LOWS, pfx_w, pfx_b, pfm_w, pfm_b, G);
    k4_out<<<512, 64, 0, stream>>>(G, pb_w, pb_b, out);
  }
}

// Round 6
// 280.162 us; speedup vs baseline: 1.4835x; 1.0716x over previous
//
#include <hip/hip_runtime.h>

#define NTOK 1024
#define KSEL 256

// Workspace layout (floats):
//   Ppart [NS][B][2][33][NTOK] : per-channel-split partial projections.
//     part0 (xt): j0 = gx_w.xt (score_x), j1..8 = px_w@xt, j9..16 = pm_w@xt,
//                 j17..24 = prx_w@xt, j25..32 = prm_w@xt
//     part1 (mt): j0 = gm_w.mt (score_m), j1..8 = px_w@mt, j9..16 = pm_w@mt,
//                 j17..24 = prx_w@mt, j25..32 = prm_w@mt
//   masks [B][4][NTOK]         : tm_x, rm_x, tm_m, rm_m (binary 0/1)
//   LOWS  [B][4][8][NTOK]      : kind 0=lowx 1=lrx 2=lowm 3=lrm

// ---------------- K1: skinny projection ----------------
// NS-way channel split for occupancy; weights staged in LDS, read as
// wave-uniform float4 (broadcast, no bank conflict).
// grid = 32b * NS * 8 ntiles * 2 parts, block = 128 (2 waves). 32 VGPR target.
template <int NS>
__global__ __launch_bounds__(128) void k1_proj(
    const float* __restrict__ x,
    const float* __restrict__ gx_w, const float* __restrict__ gm_w,
    const float* __restrict__ px_w, const float* __restrict__ pm_w,
    const float* __restrict__ prx_w, const float* __restrict__ prm_w,
    float* __restrict__ Pp)
{
  constexpr int CS = 384 / NS;
  constexpr int SB = (NS == 8) ? 3 : (NS == 4) ? 2 : 0;
  __shared__ float wlds[33 * CS];

  int blk = blockIdx.x;
  int part = blk & 1;
  int ntile = (blk >> 1) & 7;
  int s = (blk >> 4) & (NS - 1);
  int b = blk >> (4 + SB);
  int n = ntile * 128 + threadIdx.x;
  const float* gw = part ? gm_w : gx_w;
  int cw0 = s * CS;

  // stage 33 weight rows for this channel slice
  for (int idx = threadIdx.x; idx < 33 * CS; idx += 128) {
    int j = idx / CS;
    int c = idx - j * CS;
    const float* src;
    if (j == 0)       src = gw + cw0;
    else if (j < 9)   src = px_w  + (j - 1)  * 384 + cw0;
    else if (j < 17)  src = pm_w  + (j - 9)  * 384 + cw0;
    else if (j < 25)  src = prx_w + (j - 17) * 384 + cw0;
    else              src = prm_w + (j - 25) * 384 + cw0;
    wlds[idx] = src[c];
  }
  __syncthreads();

  float acc[33];
  #pragma unroll
  for (int j = 0; j < 33; ++j) acc[j] = 0.f;

  const float* xp = x + ((size_t)b * 768 + part * 384 + cw0) * NTOK + n;
  #pragma unroll 2
  for (int c4 = 0; c4 < CS / 4; ++c4) {
    float v0 = xp[(size_t)(c4 * 4 + 0) * NTOK];
    float v1 = xp[(size_t)(c4 * 4 + 1) * NTOK];
    float v2 = xp[(size_t)(c4 * 4 + 2) * NTOK];
    float v3 = xp[(size_t)(c4 * 4 + 3) * NTOK];
    #pragma unroll
    for (int j = 0; j < 33; ++j) {
      float4 w = *reinterpret_cast<const float4*>(&wlds[j * CS + c4 * 4]);
      acc[j] = fmaf(w.x, v0, acc[j]);
      acc[j] = fmaf(w.y, v1, acc[j]);
      acc[j] = fmaf(w.z, v2, acc[j]);
      acc[j] = fmaf(w.w, v3, acc[j]);
    }
  }
  float* op = Pp + ((((size_t)s * 32 + b) * 2 + part) * 33) * NTOK + n;
  #pragma unroll
  for (int j = 0; j < 33; ++j) op[(size_t)j * NTOK] = acc[j];
}

// ---------------- K2: exact stable top-k & bottom-k, one wave per row ----------------
// grid = 64 blocks (32 b x 2 branches), block = 64. Scores in registers.
__global__ __launch_bounds__(64) void k2_masks(
    const float* __restrict__ Ppart, float* __restrict__ masks, int nsplit)
{
  int b = blockIdx.x >> 1;
  int branch = blockIdx.x & 1;
  int lane = threadIdx.x;
  unsigned long long lmask = (1ull << lane) - 1ull;

  float v[16];
  #pragma unroll
  for (int i = 0; i < 16; ++i) v[i] = 0.f;
  for (int s = 0; s < nsplit; ++s) {
    const float* sp = Ppart + (((size_t)s * 32 + b) * 2 + branch) * 33 * NTOK;
    #pragma unroll
    for (int i = 0; i < 16; ++i) v[i] += sp[i * 64 + lane];
  }
  unsigned key[16];
  #pragma unroll
  for (int i = 0; i < 16; ++i) {
    float f = v[i] + 0.0f;  // canonicalize -0.0
    unsigned bits = __float_as_uint(f);
    key[i] = (bits & 0x80000000u) ? ~bits : (bits | 0x80000000u);
  }

  for (int which = 0; which < 2; ++which) {
    unsigned prefix = 0u;
    for (int bit = 31; bit >= 0; --bit) {
      unsigned cand = prefix | (1u << bit);
      int cnt = 0;
      #pragma unroll
      for (int i = 0; i < 16; ++i) {
        unsigned kk = which ? ~key[i] : key[i];
        cnt += __popcll(__ballot(kk >= cand));
      }
      if (cnt >= KSEL) prefix = cand;
    }
    int cgt = 0;
    #pragma unroll
    for (int i = 0; i < 16; ++i) {
      unsigned kk = which ? ~key[i] : key[i];
      cgt += __popcll(__ballot(kk > prefix));
    }
    int quota = KSEL - cgt;
    float* mp = masks + ((size_t)b * 4 + branch * 2 + which) * NTOK;
    int run = 0;
    #pragma unroll
    for (int i = 0; i < 16; ++i) {
      unsigned kk = which ? ~key[i] : key[i];
      bool eq = (kk == prefix);
      unsigned long long bal = __ballot(eq);
      int rank = run + __popcll(bal & lmask);
      bool sel = (kk > prefix) || (eq && rank < quota);
      mp[i * 64 + lane] = sel ? 1.0f : 0.0f;
      run += __popcll(bal);
    }
  }
}

// ---------------- K3a: split-sum + mask apply, one thread per (token, r) ----------------
// grid = 32 b * 8 r * 4 ttiles = 1024 blocks, block = 256 -> 4096 waves.
template <int NS>
__global__ __launch_bounds__(256) void k3a(
    const float* __restrict__ Ppart, const float* __restrict__ masks,
    const float* __restrict__ px_b, const float* __restrict__ pm_b,
    const float* __restrict__ prx_b, const float* __restrict__ prm_b,
    float* __restrict__ LOWS)
{
  int ttile = blockIdx.x & 3;
  int r = (blockIdx.x >> 2) & 7;
  int b = blockIdx.x >> 5;
  int n = ttile * 256 + threadIdx.x;

  float ax = 0.f, am = 0.f, bmv = 0.f, bxv = 0.f, cx = 0.f, cm = 0.f;
  #pragma unroll
  for (int s = 0; s < NS; ++s) {
    const float* P0 = Ppart + (((size_t)s * 32 + b) * 2 + 0) * 33 * NTOK + n;
    const float* P1 = Ppart + (((size_t)s * 32 + b) * 2 + 1) * 33 * NTOK + n;
    ax  += P0[(size_t)(1 + r) * NTOK];
    am  += P1[(size_t)(1 + r) * NTOK];
    bmv += P0[(size_t)(9 + r) * NTOK];
    bxv += P1[(size_t)(9 + r) * NTOK];
    cx  += P0[(size_t)(17 + r) * NTOK] + P1[(size_t)(17 + r) * NTOK];
    cm  += P0[(size_t)(25 + r) * NTOK] + P1[(size_t)(25 + r) * NTOK];
  }
  const float* mk = masks + (size_t)b * 4 * NTOK + n;
  float tmx = mk[0 * NTOK], rmx = mk[1 * NTOK];
  float tmm = mk[2 * NTOK], rmm = mk[3 * NTOK];
  float wx = 1.0f - tmx - rmx;
  float wm = 1.0f - tmm - rmm;

  float lowx = fmaf(tmx, ax, fmaf(rmx, am, px_b[r]));
  float lrx  = fmaf(wx, cx, prx_b[r]);
  float lowm = fmaf(tmm, bxv, fmaf(rmm, bmv, pm_b[r]));
  float lrm  = fmaf(wm, cm, prm_b[r]);

  float* L = LOWS + ((size_t)b * 32 + r) * NTOK + n;  // [b][kind][r][tok]
  L[0 * 8 * NTOK] = lowx;
  L[1 * 8 * NTOK] = lrx;
  L[2 * 8 * NTOK] = lowm;
  L[3 * 8 * NTOK] = lrm;
}

// ---------------- K4f: fuse matmul + rank-8 -> 384 expansion ----------------
// grid = 32 b * 4 cparts * 4 ttiles = 512 blocks, block = 64 (1 wave).
// Each thread: 4 tokens (strided by 64 within its 256-token tile).
// Fuse recomputed per cpart (1024 FMA/thread of redundancy, cheap).
__global__ __launch_bounds__(64) void k4f(
    const float* __restrict__ LOWS,
    const float* __restrict__ pfx_w, const float* __restrict__ pfx_b,
    const float* __restrict__ pfm_w, const float* __restrict__ pfm_b,
    const float* __restrict__ pb_w, const float* __restrict__ pb_b,
    float* __restrict__ out)
{
  int blk = blockIdx.x;
  int ttile = blk & 3;          // 4 tiles of 256 tokens
  int cpart = (blk >> 2) & 3;   // 4 chunks of 96 channels
  int b = blk >> 4;
  int lane = threadIdx.x;

  const float* wp = pb_w + (size_t)cpart * 96 * 8;
  const float* bp = pb_b + (size_t)cpart * 96;

  #pragma unroll
  for (int t = 0; t < 4; ++t) {
    int n = ttile * 256 + t * 64 + lane;
    const float* L = LOWS + (size_t)b * 32 * NTOK + n;
    float lows[32];
    #pragma unroll
    for (int i = 0; i < 32; ++i) lows[i] = L[(size_t)i * NTOK];

    float g[8];
    #pragma unroll
    for (int r = 0; r < 8; ++r) {
      float acc = pfx_b[r] + pfm_b[r];
      #pragma unroll
      for (int s2 = 0; s2 < 8; ++s2) {
        acc = fmaf(pfx_w[r * 16 + s2],     lows[s2],      acc);
        acc = fmaf(pfx_w[r * 16 + 8 + s2], lows[8 + s2],  acc);
        acc = fmaf(pfm_w[r * 16 + s2],     lows[16 + s2], acc);
        acc = fmaf(pfm_w[r * 16 + 8 + s2], lows[24 + s2], acc);
      }
      g[r] = acc;
    }

    float* op = out + ((size_t)b * 384 + (size_t)cpart * 96) * NTOK + n;
    #pragma unroll 4
    for (int c = 0; c < 96; ++c) {
      const float* w = wp + c * 8;
      float acc = bp[c];
      acc = fmaf(w[0], g[0], acc);
      acc = fmaf(w[1], g[1], acc);
      acc = fmaf(w[2], g[2], acc);
      acc = fmaf(w[3], g[3], acc);
      acc = fmaf(w[4], g[4], acc);
      acc = fmaf(w[5], g[5], acc);
      acc = fmaf(w[6], g[6], acc);
      acc = fmaf(w[7], g[7], acc);
      op[(size_t)c * NTOK] = acc;
    }
  }
}

extern "C" void kernel_launch(void* const* d_in, const int* in_sizes, int n_in,
                              void* d_out, int out_size, void* d_ws, size_t ws_size,
                              hipStream_t stream) {
  const float* x     = (const float*)d_in[0];
  const float* gx_w  = (const float*)d_in[1];
  const float* gm_w  = (const float*)d_in[3];
  const float* px_w  = (const float*)d_in[5];
  const float* px_b  = (const float*)d_in[6];
  const float* pm_w  = (const float*)d_in[7];
  const float* pm_b  = (const float*)d_in[8];
  const float* prx_w = (const float*)d_in[9];
  const float* prx_b = (const float*)d_in[10];
  const float* prm_w = (const float*)d_in[11];
  const float* prm_b = (const float*)d_in[12];
  const float* pfx_w = (const float*)d_in[13];
  const float* pfx_b = (const float*)d_in[14];
  const float* pfm_w = (const float*)d_in[15];
  const float* pfm_b = (const float*)d_in[16];
  const float* pb_w  = (const float*)d_in[17];
  const float* pb_b  = (const float*)d_in[18];
  float* out = (float*)d_out;

  const size_t P1_F   = 32ull * 2 * 33 * NTOK;  // one split slab (floats)
  const size_t MASK_F = 32ull * 4 * NTOK;
  const size_t LOWS_F = 32ull * 32 * NTOK;
  const size_t need8  = (8 * P1_F + MASK_F + LOWS_F) * 4;
  const size_t need4  = (4 * P1_F + MASK_F + LOWS_F) * 4;

  float* ws = (float*)d_ws;
  if (ws_size >= need8) {
    float* Ppart = ws;
    float* masks = ws + 8 * P1_F;
    float* LOWS  = masks + MASK_F;
    k1_proj<8><<<4096, 128, 0, stream>>>(x, gx_w, gm_w, px_w, pm_w, prx_w, prm_w, Ppart);
    k2_masks<<<64, 64, 0, stream>>>(Ppart, masks, 8);
    k3a<8><<<1024, 256, 0, stream>>>(Ppart, masks, px_b, pm_b, prx_b, prm_b, LOWS);
    k4f<<<512, 64, 0, stream>>>(LOWS, pfx_w, pfx_b, pfm_w, pfm_b, pb_w, pb_b, out);
  } else if (ws_size >= need4) {
    float* Ppart = ws;
    float* masks = ws + 4 * P1_F;
    float* LOWS  = masks + MASK_F;
    k1_proj<4><<<2048, 128, 0, stream>>>(x, gx_w, gm_w, px_w, pm_w, prx_w, prm_w, Ppart);
    k2_masks<<<64, 64, 0, stream>>>(Ppart, masks, 4);
    k3a<4><<<1024, 256, 0, stream>>>(Ppart, masks, px_b, pm_b, prx_b, prm_b, LOWS);
    k4f<<<512, 64, 0, stream>>>(LOWS, pfx_w, pfx_b, pfm_w, pfm_b, pb_w, pb_b, out);
  } else {
    float* Ppart = ws;
    float* masks = ws + P1_F;
    float* LOWS  = masks + MASK_F;
    k1_proj<1><<<512, 128, 0, stream>>>(x, gx_w, gm_w, px_w, pm_w, prx_w, prm_w, Ppart);
    k2_masks<<<64, 64, 0, stream>>>(Ppart, masks, 1);
    k3a<1><<<1024, 256, 0, stream>>>(Ppart, masks, px_b, pm_b, prx_b, prm_b, LOWS);
    k4f<<<512, 64, 0, stream>>>(LOWS, pfx_w, pfx_b, pfm_w, pfm_b, pb_w, pb_b, out);
  }
}

// Round 7
// 274.841 us; speedup vs baseline: 1.5123x; 1.0194x over previous
//
#include <hip/hip_runtime.h>

#define NTOK 1024
#define KSEL 256

// Workspace layout (floats):
//   Ppart [NS][B][2][33][NTOK] : per-channel-split partial projections.
//     part0 (xt): j0 = gx_w.xt (score_x), j1..8 = px_w@xt, j9..16 = pm_w@xt,
//                 j17..24 = prx_w@xt, j25..32 = prm_w@xt
//     part1 (mt): j0 = gm_w.mt (score_m), j1..8 = px_w@mt, j9..16 = pm_w@mt,
//                 j17..24 = prx_w@mt, j25..32 = prm_w@mt
//   masks [B][4][NTOK]         : tm_x, rm_x, tm_m, rm_m (binary 0/1)

// ---------------- K1: skinny projection ----------------
// No LDS: weight indices are wave-uniform -> compiler emits s_load (scalar pipe),
// FMAs read SGPR operand directly. 2 tokens/thread via float2 (512 B per wave-load).
// grid = 32b * NS * 2 parts * 4 ntiles, block = 128 (2 waves, 256 tokens).
template <int NS>
__global__ __launch_bounds__(128) void k1_proj(
    const float* __restrict__ x,
    const float* __restrict__ gx_w, const float* __restrict__ gm_w,
    const float* __restrict__ px_w, const float* __restrict__ pm_w,
    const float* __restrict__ prx_w, const float* __restrict__ prm_w,
    float* __restrict__ Pp)
{
  constexpr int CS = 384 / NS;
  constexpr int SB = (NS == 8) ? 3 : (NS == 4) ? 2 : 0;
  int blk = blockIdx.x;
  int part = blk & 1;
  int ntile = (blk >> 1) & 3;          // 4 tiles of 256 tokens
  int s = (blk >> 3) & (NS - 1);
  int b = blk >> (3 + SB);
  int n0 = ntile * 256 + threadIdx.x * 2;
  const float* gw = part ? gm_w : gx_w;
  int cw0 = s * CS;

  float2 acc[33];
  #pragma unroll
  for (int j = 0; j < 33; ++j) { acc[j].x = 0.f; acc[j].y = 0.f; }

  const float* xp = x + ((size_t)b * 768 + part * 384 + cw0) * NTOK + n0;
  #pragma unroll 8
  for (int c = 0; c < CS; ++c) {
    float2 v = *reinterpret_cast<const float2*>(xp + (size_t)c * NTOK);
    int cw = cw0 + c;
    float w0 = gw[cw];
    acc[0].x = fmaf(w0, v.x, acc[0].x);
    acc[0].y = fmaf(w0, v.y, acc[0].y);
    #pragma unroll
    for (int r = 0; r < 8; ++r) {
      float wa = px_w[r * 384 + cw];
      float wb = pm_w[r * 384 + cw];
      float wc = prx_w[r * 384 + cw];
      float wd = prm_w[r * 384 + cw];
      acc[1 + r].x  = fmaf(wa, v.x, acc[1 + r].x);
      acc[1 + r].y  = fmaf(wa, v.y, acc[1 + r].y);
      acc[9 + r].x  = fmaf(wb, v.x, acc[9 + r].x);
      acc[9 + r].y  = fmaf(wb, v.y, acc[9 + r].y);
      acc[17 + r].x = fmaf(wc, v.x, acc[17 + r].x);
      acc[17 + r].y = fmaf(wc, v.y, acc[17 + r].y);
      acc[25 + r].x = fmaf(wd, v.x, acc[25 + r].x);
      acc[25 + r].y = fmaf(wd, v.y, acc[25 + r].y);
    }
  }
  float* op = Pp + ((((size_t)s * 32 + b) * 2 + part) * 33) * NTOK + n0;
  #pragma unroll
  for (int j = 0; j < 33; ++j)
    *reinterpret_cast<float2*>(op + (size_t)j * NTOK) = acc[j];
}

// ---------------- K2: exact stable top-k & bottom-k, one wave per row ----------------
// grid = 64 blocks (32 b x 2 branches), block = 64. Scores in registers.
__global__ __launch_bounds__(64) void k2_masks(
    const float* __restrict__ Ppart, float* __restrict__ masks, int nsplit)
{
  int b = blockIdx.x >> 1;
  int branch = blockIdx.x & 1;
  int lane = threadIdx.x;
  unsigned long long lmask = (1ull << lane) - 1ull;

  float v[16];
  #pragma unroll
  for (int i = 0; i < 16; ++i) v[i] = 0.f;
  for (int s = 0; s < nsplit; ++s) {
    const float* sp = Ppart + (((size_t)s * 32 + b) * 2 + branch) * 33 * NTOK;
    #pragma unroll
    for (int i = 0; i < 16; ++i) v[i] += sp[i * 64 + lane];
  }
  unsigned key[16];
  #pragma unroll
  for (int i = 0; i < 16; ++i) {
    float f = v[i] + 0.0f;  // canonicalize -0.0
    unsigned bits = __float_as_uint(f);
    key[i] = (bits & 0x80000000u) ? ~bits : (bits | 0x80000000u);
  }

  for (int which = 0; which < 2; ++which) {
    unsigned prefix = 0u;
    for (int bit = 31; bit >= 0; --bit) {
      unsigned cand = prefix | (1u << bit);
      int cnt = 0;
      #pragma unroll
      for (int i = 0; i < 16; ++i) {
        unsigned kk = which ? ~key[i] : key[i];
        cnt += __popcll(__ballot(kk >= cand));
      }
      if (cnt >= KSEL) prefix = cand;
    }
    int cgt = 0;
    #pragma unroll
    for (int i = 0; i < 16; ++i) {
      unsigned kk = which ? ~key[i] : key[i];
      cgt += __popcll(__ballot(kk > prefix));
    }
    int quota = KSEL - cgt;
    float* mp = masks + ((size_t)b * 4 + branch * 2 + which) * NTOK;
    int run = 0;
    #pragma unroll
    for (int i = 0; i < 16; ++i) {
      unsigned kk = which ? ~key[i] : key[i];
      bool eq = (kk == prefix);
      unsigned long long bal = __ballot(eq);
      int rank = run + __popcll(bal & lmask);
      bool sel = (kk > prefix) || (eq && rank < quota);
      mp[i * 64 + lane] = sel ? 1.0f : 0.0f;
      run += __popcll(bal);
    }
  }
}

// ---------------- K3f: fused split-sum + mask + fuse matmul + 384 expansion ----------------
// grid = 32 b * 16 tiles (64 tokens) = 512 blocks, block = 256 = (tok 64) x (kind/cpart 4).
// P1: thread (tok,kind) computes 8 lows values -> LDS.
// P2: wave 0 (tok) does the 8x32 fuse matmul -> g[8] -> LDS.
// P3: thread (tok,cpart) expands 96 output channels.
template <int NS>
__global__ __launch_bounds__(256) void k3f(
    const float* __restrict__ Ppart, const float* __restrict__ masks,
    const float* __restrict__ px_b, const float* __restrict__ pm_b,
    const float* __restrict__ prx_b, const float* __restrict__ prm_b,
    const float* __restrict__ pfx_w, const float* __restrict__ pfx_b,
    const float* __restrict__ pfm_w, const float* __restrict__ pfm_b,
    const float* __restrict__ pb_w, const float* __restrict__ pb_b,
    float* __restrict__ out)
{
  __shared__ float lows[32][64];  // [kind*8+r][tok]
  __shared__ float gl[8][64];     // [r][tok]
  int tile = blockIdx.x & 15;
  int b = blockIdx.x >> 4;
  int t = threadIdx.x;
  int tok = t & 63;
  int kind = t >> 6;              // 0=lowx 1=lrx 2=lowm 3=lrm; also cpart in P3
  int n = tile * 64 + tok;

  // ---- P1 ----
  int branch = kind >> 1;         // 0 = x masks, 1 = m masks
  const float* mk = masks + ((size_t)b * 4 + branch * 2) * NTOK + n;
  float tm = mk[0];
  float rm = mk[NTOK];
  int rowbase = (kind == 0) ? 1 : (kind == 1) ? 17 : (kind == 2) ? 9 : 25;

  #pragma unroll
  for (int r = 0; r < 8; ++r) {
    float s0 = 0.f, s1 = 0.f;
    #pragma unroll
    for (int sp = 0; sp < NS; ++sp) {
      const float* P0 = Ppart + (((size_t)sp * 32 + b) * 2 + 0) * 33 * NTOK + n;
      const float* P1 = Ppart + (((size_t)sp * 32 + b) * 2 + 1) * 33 * NTOK + n;
      s0 += P0[(size_t)(rowbase + r) * NTOK];
      s1 += P1[(size_t)(rowbase + r) * NTOK];
    }
    float val;
    if (kind == 0)      val = fmaf(tm, s0, fmaf(rm, s1, px_b[r]));   // low_x
    else if (kind == 2) val = fmaf(tm, s1, fmaf(rm, s0, pm_b[r]));   // low_m
    else {
      float w = 1.0f - tm - rm;
      val = fmaf(w, s0 + s1, (kind == 1) ? prx_b[r] : prm_b[r]);     // low_res
    }
    lows[kind * 8 + r][tok] = val;
  }
  __syncthreads();

  // ---- P2 ----
  if (t < 64) {
    float L[32];
    #pragma unroll
    for (int i = 0; i < 32; ++i) L[i] = lows[i][tok];
    #pragma unroll
    for (int r = 0; r < 8; ++r) {
      float acc = pfx_b[r] + pfm_b[r];
      #pragma unroll
      for (int s2 = 0; s2 < 8; ++s2) {
        acc = fmaf(pfx_w[r * 16 + s2],     L[s2],      acc);
        acc = fmaf(pfx_w[r * 16 + 8 + s2], L[8 + s2],  acc);
        acc = fmaf(pfm_w[r * 16 + s2],     L[16 + s2], acc);
        acc = fmaf(pfm_w[r * 16 + 8 + s2], L[24 + s2], acc);
      }
      gl[r][tok] = acc;
    }
  }
  __syncthreads();

  // ---- P3 ----
  float g[8];
  #pragma unroll
  for (int r = 0; r < 8; ++r) g[r] = gl[r][tok];

  float* op = out + ((size_t)b * 384 + (size_t)kind * 96) * NTOK + n;
  const float* wp = pb_w + (size_t)kind * 96 * 8;
  const float* bp = pb_b + (size_t)kind * 96;
  #pragma unroll 4
  for (int c = 0; c < 96; ++c) {
    const float* w = wp + c * 8;
    float acc = bp[c];
    acc = fmaf(w[0], g[0], acc);
    acc = fmaf(w[1], g[1], acc);
    acc = fmaf(w[2], g[2], acc);
    acc = fmaf(w[3], g[3], acc);
    acc = fmaf(w[4], g[4], acc);
    acc = fmaf(w[5], g[5], acc);
    acc = fmaf(w[6], g[6], acc);
    acc = fmaf(w[7], g[7], acc);
    op[(size_t)c * NTOK] = acc;
  }
}

extern "C" void kernel_launch(void* const* d_in, const int* in_sizes, int n_in,
                              void* d_out, int out_size, void* d_ws, size_t ws_size,
                              hipStream_t stream) {
  const float* x     = (const float*)d_in[0];
  const float* gx_w  = (const float*)d_in[1];
  const float* gm_w  = (const float*)d_in[3];
  const float* px_w  = (const float*)d_in[5];
  const float* px_b  = (const float*)d_in[6];
  const float* pm_w  = (const float*)d_in[7];
  const float* pm_b  = (const float*)d_in[8];
  const float* prx_w = (const float*)d_in[9];
  const float* prx_b = (const float*)d_in[10];
  const float* prm_w = (const float*)d_in[11];
  const float* prm_b = (const float*)d_in[12];
  const float* pfx_w = (const float*)d_in[13];
  const float* pfx_b = (const float*)d_in[14];
  const float* pfm_w = (const float*)d_in[15];
  const float* pfm_b = (const float*)d_in[16];
  const float* pb_w  = (const float*)d_in[17];
  const float* pb_b  = (const float*)d_in[18];
  float* out = (float*)d_out;

  const size_t P1_F   = 32ull * 2 * 33 * NTOK;  // one split slab (floats)
  const size_t MASK_F = 32ull * 4 * NTOK;
  const size_t need4  = (4 * P1_F + MASK_F) * 4;

  float* ws = (float*)d_ws;
  if (ws_size >= need4) {
    float* Ppart = ws;
    float* masks = ws + 4 * P1_F;
    k1_proj<4><<<1024, 128, 0, stream>>>(x, gx_w, gm_w, px_w, pm_w, prx_w, prm_w, Ppart);
    k2_masks<<<64, 64, 0, stream>>>(Ppart, masks, 4);
    k3f<4><<<512, 256, 0, stream>>>(Ppart, masks, px_b, pm_b, prx_b, prm_b,
                                    pfx_w, pfx_b, pfm_w, pfm_b, pb_w, pb_b, out);
  } else {
    float* Ppart = ws;
    float* masks = ws + P1_F;
    k1_proj<1><<<256, 128, 0, stream>>>(x, gx_w, gm_w, px_w, pm_w, prx_w, prm_w, Ppart);
    k2_masks<<<64, 64, 0, stream>>>(Ppart, masks, 1);
    k3f<1><<<512, 256, 0, stream>>>(Ppart, masks, px_b, pm_b, prx_b, prm_b,
                                    pfx_w, pfx_b, pfm_w, pfm_b, pb_w, pb_b, out);
  }
}

// Round 8
// 250.284 us; speedup vs baseline: 1.6606x; 1.0981x over previous
//
#include <hip/hip_runtime.h>

#define NTOK 1024
#define KSEL 256

// Workspace (floats):
//   Ppart [NS][B][2][33][NTOK] : per-channel-split partial projections.
//     part0 (xt): j0 = gx.xt (score_x), j1..8 = px@xt, j9..16 = pm@xt,
//                 j17..24 = prx@xt, j25..32 = prm@xt
//     part1 (mt): j0 = gm.mt (score_m), j1..8 = px@mt, j9..16 = pm@mt,
//                 j17..24 = prx@mt, j25..32 = prm@mt
//   masks [B][4][NTOK] : tm_x, rm_x, tm_m, rm_m (binary 0/1)
//   G     [B][8][NTOK] : fuse_x + fuse_m per token

// ---------------- K1: skinny projection ----------------
// LDS-staged weights (wave-uniform ds_read_b128 broadcast, 0 conflicts —
// verified R6), 4 tokens/thread via float4 so each ds_read feeds 16 FMA
// (R6 was LDS-issue-bound at 4 FMA/read). grid = 32b*NS*2parts*2ntiles,
// block = 128 (2 waves covering 512 tokens).
template <int NS>
__global__ __launch_bounds__(128, 2) void k1_proj(
    const float* __restrict__ x,
    const float* __restrict__ gx_w, const float* __restrict__ gm_w,
    const float* __restrict__ px_w, const float* __restrict__ pm_w,
    const float* __restrict__ prx_w, const float* __restrict__ prm_w,
    float* __restrict__ Pp)
{
  constexpr int CS = 384 / NS;
  constexpr int L2NS = (NS == 8) ? 3 : 2;
  __shared__ float wlds[33 * CS];

  int blk = blockIdx.x;
  int part = blk & 1;
  int ntile = (blk >> 1) & 1;          // 2 tiles of 512 tokens
  int s = (blk >> 2) & (NS - 1);
  int b = blk >> (2 + L2NS);
  int n0 = ntile * 512 + threadIdx.x * 4;
  const float* gw = part ? gm_w : gx_w;
  int cw0 = s * CS;

  for (int idx = threadIdx.x; idx < 33 * CS; idx += 128) {
    int j = idx / CS;
    int c = idx - j * CS;
    const float* src;
    if (j == 0)       src = gw + cw0;
    else if (j < 9)   src = px_w  + (j - 1)  * 384 + cw0;
    else if (j < 17)  src = pm_w  + (j - 9)  * 384 + cw0;
    else if (j < 25)  src = prx_w + (j - 17) * 384 + cw0;
    else              src = prm_w + (j - 25) * 384 + cw0;
    wlds[idx] = src[c];
  }
  __syncthreads();

  float4 acc[33];
  #pragma unroll
  for (int j = 0; j < 33; ++j) acc[j] = make_float4(0.f, 0.f, 0.f, 0.f);

  const float* xp = x + ((size_t)b * 768 + part * 384 + cw0) * NTOK + n0;
  #pragma unroll 2
  for (int c4 = 0; c4 < CS / 4; ++c4) {
    float4 v0 = *reinterpret_cast<const float4*>(xp + (size_t)(c4 * 4 + 0) * NTOK);
    float4 v1 = *reinterpret_cast<const float4*>(xp + (size_t)(c4 * 4 + 1) * NTOK);
    float4 v2 = *reinterpret_cast<const float4*>(xp + (size_t)(c4 * 4 + 2) * NTOK);
    float4 v3 = *reinterpret_cast<const float4*>(xp + (size_t)(c4 * 4 + 3) * NTOK);
    #pragma unroll
    for (int j = 0; j < 33; ++j) {
      float4 w = *reinterpret_cast<const float4*>(&wlds[j * CS + c4 * 4]);
      acc[j].x = fmaf(w.x, v0.x, fmaf(w.y, v1.x, fmaf(w.z, v2.x, fmaf(w.w, v3.x, acc[j].x))));
      acc[j].y = fmaf(w.x, v0.y, fmaf(w.y, v1.y, fmaf(w.z, v2.y, fmaf(w.w, v3.y, acc[j].y))));
      acc[j].z = fmaf(w.x, v0.z, fmaf(w.y, v1.z, fmaf(w.z, v2.z, fmaf(w.w, v3.z, acc[j].z))));
      acc[j].w = fmaf(w.x, v0.w, fmaf(w.y, v1.w, fmaf(w.z, v2.w, fmaf(w.w, v3.w, acc[j].w))));
    }
  }
  float* op = Pp + ((((size_t)s * 32 + b) * 2 + part) * 33) * NTOK + n0;
  #pragma unroll
  for (int j = 0; j < 33; ++j)
    *reinterpret_cast<float4*>(op + (size_t)j * NTOK) = acc[j];
}

// ---------------- K2: exact stable top-k & bottom-k, one wave per row ----------------
// grid = 64 blocks (32 b x 2 branches), block = 64. Scores in registers.
__global__ __launch_bounds__(64) void k2_masks(
    const float* __restrict__ Ppart, float* __restrict__ masks, int nsplit)
{
  int b = blockIdx.x >> 1;
  int branch = blockIdx.x & 1;
  int lane = threadIdx.x;
  unsigned long long lmask = (1ull << lane) - 1ull;

  float v[16];
  #pragma unroll
  for (int i = 0; i < 16; ++i) v[i] = 0.f;
  for (int s = 0; s < nsplit; ++s) {
    const float* sp = Ppart + (((size_t)s * 32 + b) * 2 + branch) * 33 * NTOK;
    #pragma unroll
    for (int i = 0; i < 16; ++i) v[i] += sp[i * 64 + lane];
  }
  unsigned key[16];
  #pragma unroll
  for (int i = 0; i < 16; ++i) {
    float f = v[i] + 0.0f;  // canonicalize -0.0
    unsigned bits = __float_as_uint(f);
    key[i] = (bits & 0x80000000u) ? ~bits : (bits | 0x80000000u);
  }

  for (int which = 0; which < 2; ++which) {
    unsigned prefix = 0u;
    for (int bit = 31; bit >= 0; --bit) {
      unsigned cand = prefix | (1u << bit);
      int cnt = 0;
      #pragma unroll
      for (int i = 0; i < 16; ++i) {
        unsigned kk = which ? ~key[i] : key[i];
        cnt += __popcll(__ballot(kk >= cand));
      }
      if (cnt >= KSEL) prefix = cand;
    }
    int cgt = 0;
    #pragma unroll
    for (int i = 0; i < 16; ++i) {
      unsigned kk = which ? ~key[i] : key[i];
      cgt += __popcll(__ballot(kk > prefix));
    }
    int quota = KSEL - cgt;
    float* mp = masks + ((size_t)b * 4 + branch * 2 + which) * NTOK;
    int run = 0;
    #pragma unroll
    for (int i = 0; i < 16; ++i) {
      unsigned kk = which ? ~key[i] : key[i];
      bool eq = (kk == prefix);
      unsigned long long bal = __ballot(eq);
      int rank = run + __popcll(bal & lmask);
      bool sel = (kk > prefix) || (eq && rank < quota);
      mp[i * 64 + lane] = sel ? 1.0f : 0.0f;
      run += __popcll(bal);
    }
  }
}

// ---------------- K3g: split-sum + mask + fuse matmul -> G ----------------
// grid = 32 b * 16 tiles = 512 blocks, block = 256 = (tok 64) x (kind 4).
// Each thread: 8r x 2parts x NS independent coalesced loads -> lows in LDS;
// wave 0 then does the 8x32 fuse matmul and writes G (coalesced).
template <int NS>
__global__ __launch_bounds__(256) void k3g(
    const float* __restrict__ Ppart, const float* __restrict__ masks,
    const float* __restrict__ px_b, const float* __restrict__ pm_b,
    const float* __restrict__ prx_b, const float* __restrict__ prm_b,
    const float* __restrict__ pfx_w, const float* __restrict__ pfx_b,
    const float* __restrict__ pfm_w, const float* __restrict__ pfm_b,
    float* __restrict__ G)
{
  __shared__ float lows[32][64];  // [kind*8+r][tok]
  int tile = blockIdx.x & 15;
  int b = blockIdx.x >> 4;
  int t = threadIdx.x;
  int tok = t & 63;
  int kind = t >> 6;              // wave-uniform: 0=lowx 1=lrx 2=lowm 3=lrm
  int n = tile * 64 + tok;

  int branch = kind >> 1;
  const float* mk = masks + ((size_t)b * 4 + branch * 2) * NTOK + n;
  float tm = mk[0];
  float rm = mk[NTOK];
  int rowbase = (kind == 0) ? 1 : (kind == 1) ? 17 : (kind == 2) ? 9 : 25;

  #pragma unroll
  for (int r = 0; r < 8; ++r) {
    float s0 = 0.f, s1 = 0.f;
    #pragma unroll
    for (int sp = 0; sp < NS; ++sp) {
      const float* P0 = Ppart + (((size_t)sp * 32 + b) * 2 + 0) * 33 * NTOK + n;
      const float* P1 = Ppart + (((size_t)sp * 32 + b) * 2 + 1) * 33 * NTOK + n;
      s0 += P0[(size_t)(rowbase + r) * NTOK];
      s1 += P1[(size_t)(rowbase + r) * NTOK];
    }
    float val;
    if (kind == 0)      val = fmaf(tm, s0, fmaf(rm, s1, px_b[r]));   // low_x
    else if (kind == 2) val = fmaf(tm, s1, fmaf(rm, s0, pm_b[r]));   // low_m
    else {
      float w = 1.0f - tm - rm;
      val = fmaf(w, s0 + s1, (kind == 1) ? prx_b[r] : prm_b[r]);     // low_res
    }
    lows[kind * 8 + r][tok] = val;
  }
  __syncthreads();

  if (t < 64) {
    float L[32];
    #pragma unroll
    for (int i = 0; i < 32; ++i) L[i] = lows[i][tok];
    #pragma unroll
    for (int r = 0; r < 8; ++r) {
      float acc = pfx_b[r] + pfm_b[r];
      #pragma unroll
      for (int s2 = 0; s2 < 8; ++s2) {
        acc = fmaf(pfx_w[r * 16 + s2],     L[s2],      acc);
        acc = fmaf(pfx_w[r * 16 + 8 + s2], L[8 + s2],  acc);
        acc = fmaf(pfm_w[r * 16 + s2],     L[16 + s2], acc);
        acc = fmaf(pfm_w[r * 16 + 8 + s2], L[24 + s2], acc);
      }
      G[((size_t)b * 8 + r) * NTOK + n] = acc;
    }
  }
}

// ---------------- K4: rank-8 -> 384 expansion ----------------
// grid = 32 b * 8 cparts * 4 ttiles = 1024 blocks (4096 waves), block = 256.
// pb_w slice staged in LDS (wave-uniform b128 broadcast reads).
__global__ __launch_bounds__(256) void k4_out(
    const float* __restrict__ G, const float* __restrict__ pb_w,
    const float* __restrict__ pb_b, float* __restrict__ out)
{
  __shared__ float wl[48 * 8 + 48];
  int blk = blockIdx.x;
  int ttile = blk & 3;          // 4 tiles of 256 tokens
  int cpart = (blk >> 2) & 7;   // 8 chunks of 48 channels
  int b = blk >> 5;
  int c0 = cpart * 48;

  for (int idx = threadIdx.x; idx < 48 * 8 + 48; idx += 256)
    wl[idx] = (idx < 384) ? pb_w[(size_t)c0 * 8 + idx] : pb_b[c0 + idx - 384];
  __syncthreads();

  int n = ttile * 256 + threadIdx.x;
  float g[8];
  #pragma unroll
  for (int r = 0; r < 8; ++r) g[r] = G[((size_t)b * 8 + r) * NTOK + n];

  float* op = out + ((size_t)b * 384 + c0) * NTOK + n;
  #pragma unroll 4
  for (int c = 0; c < 48; ++c) {
    float4 w0 = *reinterpret_cast<const float4*>(&wl[c * 8]);
    float4 w1 = *reinterpret_cast<const float4*>(&wl[c * 8 + 4]);
    float acc = wl[384 + c];
    acc = fmaf(w0.x, g[0], acc);
    acc = fmaf(w0.y, g[1], acc);
    acc = fmaf(w0.z, g[2], acc);
    acc = fmaf(w0.w, g[3], acc);
    acc = fmaf(w1.x, g[4], acc);
    acc = fmaf(w1.y, g[5], acc);
    acc = fmaf(w1.z, g[6], acc);
    acc = fmaf(w1.w, g[7], acc);
    op[(size_t)c * NTOK] = acc;
  }
}

extern "C" void kernel_launch(void* const* d_in, const int* in_sizes, int n_in,
                              void* d_out, int out_size, void* d_ws, size_t ws_size,
                              hipStream_t stream) {
  const float* x     = (const float*)d_in[0];
  const float* gx_w  = (const float*)d_in[1];
  const float* gm_w  = (const float*)d_in[3];
  const float* px_w  = (const float*)d_in[5];
  const float* px_b  = (const float*)d_in[6];
  const float* pm_w  = (const float*)d_in[7];
  const float* pm_b  = (const float*)d_in[8];
  const float* prx_w = (const float*)d_in[9];
  const float* prx_b = (const float*)d_in[10];
  const float* prm_w = (const float*)d_in[11];
  const float* prm_b = (const float*)d_in[12];
  const float* pfx_w = (const float*)d_in[13];
  const float* pfx_b = (const float*)d_in[14];
  const float* pfm_w = (const float*)d_in[15];
  const float* pfm_b = (const float*)d_in[16];
  const float* pb_w  = (const float*)d_in[17];
  const float* pb_b  = (const float*)d_in[18];
  float* out = (float*)d_out;

  const size_t P1_F   = 32ull * 2 * 33 * NTOK;  // one split slab (floats)
  const size_t MASK_F = 32ull * 4 * NTOK;
  const size_t G_F    = 32ull * 8 * NTOK;
  const size_t need8  = (8 * P1_F + MASK_F + G_F) * 4;
  const size_t need4  = (4 * P1_F + MASK_F + G_F) * 4;

  float* ws = (float*)d_ws;
  if (ws_size >= need8) {
    float* Ppart = ws;
    float* masks = ws + 8 * P1_F;
    float* G     = masks + MASK_F;
    k1_proj<8><<<1024, 128, 0, stream>>>(x, gx_w, gm_w, px_w, pm_w, prx_w, prm_w, Ppart);
    k2_masks<<<64, 64, 0, stream>>>(Ppart, masks, 8);
    k3g<8><<<512, 256, 0, stream>>>(Ppart, masks, px_b, pm_b, prx_b, prm_b,
                                    pfx_w, pfx_b, pfm_w, pfm_b, G);
    k4_out<<<1024, 256, 0, stream>>>(G, pb_w, pb_b, out);
  } else {
    float* Ppart = ws;
    float* masks = ws + 4 * P1_F;
    float* G     = masks + MASK_F;
    k1_proj<4><<<512, 128, 0, stream>>>(x, gx_w, gm_w, px_w, pm_w, prx_w, prm_w, Ppart);
    k2_masks<<<64, 64, 0, stream>>>(Ppart, masks, 4);
    k3g<4><<<512, 256, 0, stream>>>(Ppart, masks, px_b, pm_b, prx_b, prm_b,
                                    pfx_w, pfx_b, pfm_w, pfm_b, G);
    k4_out<<<1024, 256, 0, stream>>>(G, pb_w, pb_b, out);
  }
}